// Round 6
// baseline (405.389 us; speedup 1.0000x reference)
//
#include <hip/hip_runtime.h>

// SpectralLayer reduction (algebra verified; fp32 buffers confirmed):
//   out[:, :512]  = data[:, :512]                        (exact pass-through)
//   out[:, 512+n] = relu( d_n*data[:,512+n] + (1-d_n)*t_n ),
//       t = data[:, :512] @ W^T,  W[n][k] = base[512+n][k],  d = v^2 - v + 1
// Round 11: de-serialize phases. r10's copy blocks shared the kernel's static
// 68KB LDS allocation -> no co-residency (2 blocks/CU total), phases stayed
// lockstep: HBM prologue | L2-only k-loop (HBM idle) | HBM epilogue.
// Fix: drop copy blocks; each GEMM block copies its OWN 64 rows' lower half
// INSIDE the k-loop (1 float4 load + 1 store per thread per k-iter, 2-deep
// static pipeline). Load is an L2/L3 re-read of bytes the prologue just
// fetched (no new HBM fetch); store gives the k-loop a continuous HBM write
// stream overlapping the L2-bound MFMA/LDW work. Everything else = r10.

typedef float f32x4 __attribute__((ext_vector_type(4)));
typedef int   i32x4 __attribute__((ext_vector_type(4)));

#define DIMW   1024
#define HALFD  512
#define BM     64
#define LDAP   520         // padded LDS row stride (elements); 1040 B = 65*16
#define NITER  16          // K = 512, BK = 32

__device__ __forceinline__ unsigned short f2bf(float x) {
    union { float f; unsigned int i; } c;
    c.f = x;
    unsigned int r = c.i + 0x7FFFu + ((c.i >> 16) & 1u);  // round-nearest-even
    return (unsigned short)(r >> 16);
}
__device__ __forceinline__ unsigned int pack2(float a, float b) {
    return (unsigned int)f2bf(a) | ((unsigned int)f2bf(b) << 16);
}

// D(f32x4) += A(8 bf16 in 4 VGPRs) * B(8 bf16 in 4 VGPRs); C tied to D.
__device__ __forceinline__ void mfma_16x16x32_bf16(f32x4& d, const i32x4& a, const i32x4& b) {
    asm volatile("v_mfma_f32_16x16x32_bf16 %0, %1, %2, %0"
                 : "+v"(d)
                 : "v"(a), "v"(b));
}
// Hazard fence: VALU may not read an MFMA result for ~8 cycles.
__device__ __forceinline__ void acc_fence(f32x4& d) {
    asm volatile("s_nop 7\n\ts_nop 7" : "+v"(d));
}

__global__ __launch_bounds__(512, 4) void spectral_kernel(
    const float* __restrict__ data,
    const float* __restrict__ wsrc,   // base: W at rows [512,1024), cols [0,512)
    const float* __restrict__ td,
    const float* __restrict__ tdm,
    const float* __restrict__ ud,
    float* __restrict__ out)
{
    __shared__ unsigned short As[BM * LDAP];   // 66,560 B
    __shared__ float dsh[HALFD];               //  2,048 B

    const int tid    = (int)threadIdx.x;
    const int lane   = tid & 63;
    const int wn     = tid >> 6;               // wave 0..7 -> col panel wn*64
    const int lane16 = lane & 15;
    const int quad   = lane >> 4;
    const int rowBase = (int)blockIdx.x * BM;

    // d[n] for all 512 output cols (diag entries at [512+n][512+n])
    {
        int j = HALFD + tid;
        size_t fi = (size_t)j * DIMW + j;
        dsh[tid] = td[fi] * tdm[fi] + ud[fi];
    }

    // ---- Stage A once (bf16, padded-linear) : 8-deep load batches ----
    #pragma unroll
    for (int h = 0; h < 2; ++h) {
        float4 v[8];
        #pragma unroll
        for (int p = 0; p < 8; ++p) {
            int c  = (h * 8 + p) * 512 + tid;
            int r  = c >> 7;
            int cc = c & 127;
            v[p] = *(const float4*)(data + (size_t)(rowBase + r) * DIMW + cc * 4);
        }
        #pragma unroll
        for (int p = 0; p < 8; ++p) {
            int c  = (h * 8 + p) * 512 + tid;
            int r  = c >> 7;
            int cc = c & 127;
            uint2 uu;
            uu.x = pack2(v[p].x, v[p].y);
            uu.y = pack2(v[p].z, v[p].w);
            *(uint2*)(As + r * LDAP + cc * 4) = uu;
        }
    }

    i32x4 b0[4], b1[4];  // 1-deep W prefetch (named sets, static indexing)

    // W fragment: lane holds W[col = wn*64 + ni*16 + lane16][k .. k+7],
    // loaded fp32 (two float4) + packed in-register. L2-resident (1 MB).
    auto LDW = [&](int it, i32x4 (&b)[4]) {
        #pragma unroll
        for (int ni = 0; ni < 4; ++ni) {
            int col = wn * 64 + ni * 16 + lane16;
            const float* p = wsrc + (size_t)(HALFD + col) * DIMW + it * 32 + quad * 8;
            float4 f0 = *(const float4*)p;
            float4 f1 = *(const float4*)(p + 4);
            i32x4 t;
            t[0] = (int)pack2(f0.x, f0.y);  t[1] = (int)pack2(f0.z, f0.w);
            t[2] = (int)pack2(f1.x, f1.y);  t[3] = (int)pack2(f1.z, f1.w);
            b[ni] = t;
        }
    };

    LDW(0, b0);
    LDW(1, b1);
    __syncthreads();    // the ONLY barrier in the kernel

    f32x4 acc[4][4];    // acc[mi][ni]: data-rows mi*16+lane16, w-cols ni*16+quad*4+r
    #pragma unroll
    for (int mi = 0; mi < 4; ++mi)
        #pragma unroll
        for (int ni = 0; ni < 4; ++ni)
            acc[mi][ni] = (f32x4){0.f, 0.f, 0.f, 0.f};

    // SWAPPED operands: mfma(acc, W-frag, data-frag).
    // D-row axis (quad*4+reg) <- A-operand (W) lane16 axis = w-col;
    // D-col axis (lane16)     <- B-operand (data) lane16 axis = data-row.
    auto STEP = [&](int it, i32x4 (&b)[4]) {
        i32x4 a[4];
        #pragma unroll
        for (int mi = 0; mi < 4; ++mi)
            a[mi] = *(const i32x4*)(As + (mi * 16 + lane16) * LDAP + it * 32 + quad * 8);
        #pragma unroll
        for (int mi = 0; mi < 4; ++mi)
            #pragma unroll
            for (int ni = 0; ni < 4; ++ni)
                mfma_16x16x32_bf16(acc[mi][ni], b[ni], a[mi]);
    };

    // Copy weave: chunk c(it) = it*512 + tid of the block's lower-half rows.
    // Loaded at iter it (L2/L3 re-read), stored at iter it+2 (HBM write
    // overlapping the k-loop). cp[] has static indices only (loop unrolled).
    float4 cp[NITER];
    auto CPL = [&](int it) {
        int c  = it * 512 + tid;
        int r  = c >> 7;
        int cc = c & 127;
        cp[it] = *(const float4*)(data + (size_t)(rowBase + r) * DIMW + cc * 4);
    };
    auto CPS = [&](int it) {
        int c  = it * 512 + tid;
        int r  = c >> 7;
        int cc = c & 127;
        *(float4*)(out + (size_t)(rowBase + r) * DIMW + cc * 4) = cp[it];
    };

    #pragma unroll
    for (int ib = 0; ib < 8; ++ib) {
        const int it = ib * 2;
        CPL(it);
        STEP(it, b0);
        if (it + 2 < NITER) LDW(it + 2, b0);
        if (it >= 2) CPS(it - 2);
        CPL(it + 1);
        STEP(it + 1, b1);
        if (it + 3 < NITER) LDW(it + 3, b1);
        if (it >= 2) CPS(it - 1);
    }
    CPS(14);
    CPS(15);

    #pragma unroll
    for (int mi = 0; mi < 4; ++mi)
        #pragma unroll
        for (int ni = 0; ni < 4; ++ni)
            acc_fence(acc[mi][ni]);

    // Epilogue (vectorized): per (mi,ni) lane handles row = rowBase+mi*16+lane16,
    // cols 512 + wn*64 + ni*16 + quad*4 .. +4  -> float4 load/compute/store.
    #pragma unroll
    for (int mi = 0; mi < 4; ++mi) {
        const int row = rowBase + mi * 16 + lane16;
        const float* drow = data + (size_t)row * DIMW + HALFD;
        float*       orow = out  + (size_t)row * DIMW + HALFD;
        #pragma unroll
        for (int ni = 0; ni < 4; ++ni) {
            const int colb = wn * 64 + ni * 16 + quad * 4;
            float4 u1 = *(const float4*)(drow + colb);
            float4 d4 = *(const float4*)(dsh + colb);
            float4 o;
            o.x = fmaxf(d4.x * u1.x + (1.0f - d4.x) * acc[mi][ni][0], 0.0f);
            o.y = fmaxf(d4.y * u1.y + (1.0f - d4.y) * acc[mi][ni][1], 0.0f);
            o.z = fmaxf(d4.z * u1.z + (1.0f - d4.z) * acc[mi][ni][2], 0.0f);
            o.w = fmaxf(d4.w * u1.w + (1.0f - d4.w) * acc[mi][ni][3], 0.0f);
            *(float4*)(orow + colb) = o;
        }
    }
}

extern "C" void kernel_launch(void* const* d_in, const int* in_sizes, int n_in,
                              void* d_out, int out_size, void* d_ws, size_t ws_size,
                              hipStream_t stream) {
    // setup_inputs order: 0 data, 1 base, 2 base_mask, 3 eye, 4 trainable_diag,
    //                     5 trainable_diag_mask, 6 untrainable_diag, 7 mask1, 8 mask2
    const float* data = (const float*)d_in[0];
    const float* base = (const float*)d_in[1];
    const float* td   = (const float*)d_in[4];
    const float* tdm  = (const float*)d_in[5];
    const float* ud   = (const float*)d_in[6];
    float* out = (float*)d_out;

    dim3 block(512, 1, 1);
    dim3 grid(32768 / BM, 1, 1);               // 512 GEMM blocks = 2 per CU
    spectral_kernel<<<grid, block, 0, stream>>>(data, base, td, tdm, ud, out);
}